// Round 4
// baseline (471.858 us; speedup 1.0000x reference)
//
#include <hip/hip_runtime.h>
#include <cstdint>

typedef int   i32x4 __attribute__((ext_vector_type(4)));
typedef int   i32x8 __attribute__((ext_vector_type(8)));
typedef float f32x4 __attribute__((ext_vector_type(4)));

static constexpr int N_IMG = 32, HWP = 3136, KK = 2304, HP = 58;
static constexpr size_t XPAD_BYTES = (size_t)N_IMG * HP * HP * 256;   // 27,553,792
static constexpr size_t OFF_XPAD = 0;
static constexpr size_t OFF_WSGN = XPAD_BYTES;                         // +589,824
static constexpr size_t OFF_MSC  = OFF_WSGN + (size_t)256 * KK;
static constexpr size_t OFF_ACC  = OFF_MSC + 1024;

__device__ __forceinline__ void async16(const void* g, const void* l) {
    __builtin_amdgcn_global_load_lds(
        (const __attribute__((address_space(1))) uint32_t*)g,
        (__attribute__((address_space(3))) uint32_t*)l, 16, 0, 0);
}

__device__ __forceinline__ unsigned char sign_fp8(float v) {
    return (v > 0.f) ? 0x38u : ((v < 0.f) ? 0xB8u : 0u);   // e4m3: +1 / -1 / 0
}

// X-tile K-slice byte offset within a padded NHWC row for K-step kt (K=128)
__device__ __forceinline__ int xoff(int kt) {
    int rs = kt >> 1, rr = rs / 3, ss = rs - rr * 3;
    return (rr * HP + ss) * 256 + ((kt & 1) << 7);
}

// ---- K1: weights -> signs in MFMA-fragment order + msc + zero acc32 ----
// wA[kt][fb][hi][lane][16] : lane = quad*16 + r16 ;
// element = sign(w[ko = fb*16 + r16][k = kt*128 + quad*32 + hi*16 + j])
__global__ __launch_bounds__(256) void k_wm(const float* __restrict__ w,
                                            unsigned char* __restrict__ wA,
                                            float* __restrict__ msc,
                                            float* __restrict__ acc32) {
    int ko = blockIdx.x, t = threadIdx.x;
    __shared__ unsigned char s[2304];
    __shared__ float red[4];
    float sum = 0.f;
    #pragma unroll
    for (int i = 0; i < 9; ++i) {
        float v = w[(size_t)ko * KK + i * 256 + t];   // flat idx = c*9+rs order
        sum += fabsf(v);
        s[i * 256 + t] = sign_fp8(v);
    }
    #pragma unroll
    for (int off = 32; off; off >>= 1) sum += __shfl_down(sum, off, 64);
    if ((t & 63) == 0) red[t >> 6] = sum;
    __syncthreads();
    if (t == 0) msc[ko] = (red[0] + red[1] + red[2] + red[3]) * (1.f / 2304.f);
    if (ko == 0 && t < 32) acc32[t] = 0.f;
    int fb = ko >> 4, r16 = ko & 15;
    int quad = (t >> 5) & 3, hi = (t >> 4) & 1, j = t & 15;
    int lane = quad * 16 + r16;
    #pragma unroll
    for (int rsidx = 0; rsidx < 9; ++rsidx) {
        int kt = rsidx * 2 + (t >> 7);                  // k = rsidx*256 + t
        wA[(((size_t)kt * 16 + fb) * 2 + hi) * 1024 + lane * 16 + j] = s[t * 9 + rsidx];
    }
}

// ---- K2: x -> signs (fp8, padded NHWC) + per-sample |x| sum + halo clear ----
__global__ __launch_bounds__(256) void k_xpad(const float* __restrict__ x,
                                              unsigned char* __restrict__ xpad,
                                              float* __restrict__ acc32) {
    int bx = blockIdx.x, n = blockIdx.y;
    // halo clear: 32 n * 228 border cells * 16 lanes of 16B, spread over the grid
    {
        int g = (n * 196 + bx) * 256 + threadIdx.x;
        if (g < 32 * 228 * 16) {
            int n2 = g / 3648, rem = g - n2 * 3648;
            int pos = rem >> 4, j = rem & 15;
            int h, wq;
            if (pos < 58)       { h = 0;         wq = pos; }
            else if (pos < 116) { h = 57;        wq = pos - 58; }
            else if (pos < 172) { h = pos - 115; wq = 0; }
            else                { h = pos - 171; wq = 57; }
            *(i32x4*)&xpad[(((size_t)n2 * HP + h) * HP + wq) * 256 + j * 16] =
                (i32x4){0, 0, 0, 0};
        }
    }
    int hwt = bx % 49, ct = bx / 49;
    int hw0 = hwt * 64, c0 = ct * 64;
    int t = threadIdx.x, hwl = t & 63, cb = t >> 6;
    __shared__ unsigned char tile[64][68];
    __shared__ float red[4];
    float asum = 0.f;
    #pragma unroll
    for (int cc = 0; cc < 16; ++cc) {
        int cl = cb + cc * 4;
        float v = x[((size_t)(n * 256 + c0 + cl)) * HWP + hw0 + hwl];
        asum += fabsf(v);
        tile[hwl][cl] = sign_fp8(v);
    }
    #pragma unroll
    for (int off = 32; off; off >>= 1) asum += __shfl_down(asum, off, 64);
    if ((t & 63) == 0) red[t >> 6] = asum;
    __syncthreads();
    if (t == 0) atomicAdd(&acc32[n], red[0] + red[1] + red[2] + red[3]);
    int j = t & 15, rg = t >> 4;
    #pragma unroll
    for (int ps = 0; ps < 4; ++ps) {
        int hl = ps * 16 + rg;
        int hw = hw0 + hl, h = hw / 56, wp = hw - h * 56;
        unsigned int v4 = *(const unsigned int*)&tile[hl][4 * j];
        *(unsigned int*)&xpad[(((size_t)n * HP + h + 1) * HP + (wp + 1)) * 256 + c0 + 4 * j] = v4;
    }
}

// ---- K3: MX-fp8 implicit GEMM, A coalesced global->reg, X via LDS dbuf ----
// M=ko (2x128 grid.x), N=p (784x128 grid.y), K=2304 (18 steps of 128)
__global__ __launch_bounds__(256, 3) void k_gemm(const unsigned char* __restrict__ wA,
                                                 const unsigned char* __restrict__ xpad,
                                                 const float* __restrict__ acc32,
                                                 const float* __restrict__ msc,
                                                 float* __restrict__ out) {
    __shared__ __attribute__((aligned(16))) unsigned char Xt[2][128 * 128];
    const int t = threadIdx.x;
    const int lane = t & 63, wv = t >> 6;
    const int mtile = blockIdx.x, ntile = blockIdx.y;
    const int quad = lane >> 4, r16 = lane & 15;
    const int wm = wv & 1, wn = wv >> 1;

    // X staging: lane l -> LDS slot base+l*16 => row=(wv*4+rnd)*8+(l>>3), phys cg=l&7.
    // Stored logical chunk kc at phys perm(kc)^sw, perm(kc)=(kc>>1)|((kc&1)<<2), sw=row&7.
    const int lrow = lane >> 3;
    const int pxs  = (lane & 7) ^ lrow;
    const int kc   = ((pxs & 3) << 1) | (pxs >> 2);
    const unsigned char* xp[4];
    #pragma unroll
    for (int rnd = 0; rnd < 4; ++rnd) {
        int row = (wv * 4 + rnd) * 8 + lrow;
        int p = ntile * 128 + row;
        int nimg = p / HWP, hw = p - nimg * HWP;
        int h = hw / 56, wpos = hw - h * 56;
        xp[rnd] = xpad + (((size_t)nimg * HP + h) * HP + wpos) * 256 + kc * 16;
    }

    // A: wA[kt][fb][hi][lane][16]; this wave needs fb = mtile*8 + wm*4 + i.
    // Per instruction: all 64 lanes read base + lane*16 -> one coalesced 1KB burst.
    const unsigned char* wbase =
        wA + ((size_t)(mtile * 8 + wm * 4) * 2) * 1024 + lane * 16;
    // frag i lo: wbase + i*2048 + kt*32768 ; hi: +1024

    f32x4 acc[4][4];
    #pragma unroll
    for (int i = 0; i < 4; ++i)
        #pragma unroll
        for (int j = 0; j < 4; ++j)
            acc[i][j] = (f32x4){0.f, 0.f, 0.f, 0.f};

    i32x4 aLo[2][4], aHi[2][4];

    // prologue: stage X[0], load A[0]
    #pragma unroll
    for (int rnd = 0; rnd < 4; ++rnd)
        async16(xp[rnd] + xoff(0), Xt[0] + (wv * 4 + rnd) * 1024);
    #pragma unroll
    for (int i = 0; i < 4; ++i) {
        aLo[0][i] = *(const i32x4*)(wbase + i * 2048);
        aHi[0][i] = *(const i32x4*)(wbase + i * 2048 + 1024);
    }
    __syncthreads();

    #pragma unroll 2
    for (int kt = 0; kt < 18; ++kt) {
        const int cur = kt & 1;
        if (kt < 17) {
            int o = xoff(kt + 1);
            #pragma unroll
            for (int rnd = 0; rnd < 4; ++rnd)
                async16(xp[rnd] + o, Xt[1 - cur] + (wv * 4 + rnd) * 1024);
            const unsigned char* wnext = wbase + (size_t)(kt + 1) * 32768;
            #pragma unroll
            for (int i = 0; i < 4; ++i) {
                aLo[1 - cur][i] = *(const i32x4*)(wnext + i * 2048);
                aHi[1 - cur][i] = *(const i32x4*)(wnext + i * 2048 + 1024);
            }
        }
        // B fragments from LDS (perm swizzle: lo at q^sw, hi at (q|4)^sw)
        i32x8 b8[4];
        #pragma unroll
        for (int j = 0; j < 4; ++j) {
            int row = wn * 64 + j * 16 + r16, sw = row & 7;
            i32x4 lo = *(const i32x4*)(Xt[cur] + row * 128 + ((quad ^ sw) << 4));
            i32x4 hi = *(const i32x4*)(Xt[cur] + row * 128 + (((quad | 4) ^ sw) << 4));
            b8[j] = __builtin_shufflevector(lo, hi, 0, 1, 2, 3, 4, 5, 6, 7);
        }
        #pragma unroll
        for (int i = 0; i < 4; ++i) {
            i32x8 a8 = __builtin_shufflevector(aLo[cur][i], aHi[cur][i],
                                               0, 1, 2, 3, 4, 5, 6, 7);
            #pragma unroll
            for (int j = 0; j < 4; ++j)
                acc[i][j] = __builtin_amdgcn_mfma_scale_f32_16x16x128_f8f6f4(
                    a8, b8[j], acc[i][j], 0, 0, 0, 127, 0, 127);
        }
        __syncthreads();
    }

    // epilogue: D row (quad*4+reg)=ko, D col (lane&15)=p
    float mscv[4][4];
    #pragma unroll
    for (int i = 0; i < 4; ++i) {
        int ko0 = mtile * 128 + wm * 64 + i * 16 + quad * 4;
        #pragma unroll
        for (int r = 0; r < 4; ++r) mscv[i][r] = msc[ko0 + r];
    }
    #pragma unroll
    for (int j = 0; j < 4; ++j) {
        int p = ntile * 128 + wn * 64 + j * 16 + r16;
        int nimg = p / HWP, hw = p - nimg * HWP;
        float av = fmaxf(acc32[nimg] * (2.f / 802816.f), 1e-5f);
        float* outp = out + (size_t)nimg * 802816 + hw;
        #pragma unroll
        for (int i = 0; i < 4; ++i) {
            int ko0 = mtile * 128 + wm * 64 + i * 16 + quad * 4;
            #pragma unroll
            for (int r = 0; r < 4; ++r)
                outp[(size_t)(ko0 + r) * HWP] = acc[i][j][r] * av * mscv[i][r];
        }
    }
}

extern "C" void kernel_launch(void* const* d_in, const int* in_sizes, int n_in,
                              void* d_out, int out_size, void* d_ws, size_t ws_size,
                              hipStream_t stream) {
    const float* x = (const float*)d_in[0];
    const float* w = (const float*)d_in[1];
    float* out = (float*)d_out;
    char* ws = (char*)d_ws;
    unsigned char* xpad = (unsigned char*)(ws + OFF_XPAD);
    unsigned char* wA   = (unsigned char*)(ws + OFF_WSGN);
    float* msc   = (float*)(ws + OFF_MSC);
    float* acc32 = (float*)(ws + OFF_ACC);

    k_wm<<<256, 256, 0, stream>>>(w, wA, msc, acc32);
    k_xpad<<<dim3(196, N_IMG), 256, 0, stream>>>(x, xpad, acc32);
    k_gemm<<<dim3(2, 784), 256, 0, stream>>>(wA, xpad, acc32, msc, out);
}

// Round 5
// 428.725 us; speedup vs baseline: 1.1006x; 1.1006x over previous
//
#include <hip/hip_runtime.h>
#include <cstdint>

typedef int   i32x4 __attribute__((ext_vector_type(4)));
typedef int   i32x8 __attribute__((ext_vector_type(8)));
typedef float f32x4 __attribute__((ext_vector_type(4)));

static constexpr int N_IMG = 32, HWP = 3136, KK = 2304, HP = 58;
static constexpr size_t XPAD_BYTES = (size_t)N_IMG * HP * HP * 256;   // 27,553,792
static constexpr size_t OFF_XPAD = 0;
static constexpr size_t OFF_WSGN = XPAD_BYTES;                         // +589,824
static constexpr size_t OFF_MSC  = OFF_WSGN + (size_t)256 * KK;
static constexpr size_t OFF_ACC  = OFF_MSC + 1024;

__device__ __forceinline__ void async16(const void* g, const void* l) {
    __builtin_amdgcn_global_load_lds(
        (const __attribute__((address_space(1))) uint32_t*)g,
        (__attribute__((address_space(3))) uint32_t*)l, 16, 0, 0);
}

__device__ __forceinline__ unsigned char sign_fp8(float v) {
    return (v > 0.f) ? 0x38u : ((v < 0.f) ? 0xB8u : 0u);   // e4m3: +1 / -1 / 0
}

// X-tile K-slice byte offset within a padded NHWC row for K-step kt (K=128)
__device__ __forceinline__ int xoff(int kt) {
    int rs = kt >> 1, rr = rs / 3, ss = rs - rr * 3;
    return (rr * HP + ss) * 256 + ((kt & 1) << 7);
}

// ---- K1: weights -> signs in MFMA-fragment order + msc + zero acc32 ----
// wA[kt][fb][hi][lane][16] : lane = quad*16 + r16 ;
// element = sign(w[ko = fb*16 + r16][k = kt*128 + quad*32 + hi*16 + j])
__global__ __launch_bounds__(256) void k_wm(const float* __restrict__ w,
                                            unsigned char* __restrict__ wA,
                                            float* __restrict__ msc,
                                            float* __restrict__ acc32) {
    int ko = blockIdx.x, t = threadIdx.x;
    __shared__ unsigned char s[2304];
    __shared__ float red[4];
    float sum = 0.f;
    #pragma unroll
    for (int i = 0; i < 9; ++i) {
        float v = w[(size_t)ko * KK + i * 256 + t];   // flat idx = c*9+rs order
        sum += fabsf(v);
        s[i * 256 + t] = sign_fp8(v);
    }
    #pragma unroll
    for (int off = 32; off; off >>= 1) sum += __shfl_down(sum, off, 64);
    if ((t & 63) == 0) red[t >> 6] = sum;
    __syncthreads();
    if (t == 0) msc[ko] = (red[0] + red[1] + red[2] + red[3]) * (1.f / 2304.f);
    if (ko == 0 && t < 32) acc32[t] = 0.f;
    int fb = ko >> 4, r16 = ko & 15;
    int quad = (t >> 5) & 3, hi = (t >> 4) & 1, j = t & 15;
    int lane = quad * 16 + r16;
    #pragma unroll
    for (int rsidx = 0; rsidx < 9; ++rsidx) {
        int kt = rsidx * 2 + (t >> 7);                  // k = rsidx*256 + t
        wA[(((size_t)kt * 16 + fb) * 2 + hi) * 1024 + lane * 16 + j] = s[t * 9 + rsidx];
    }
}

// ---- K2: x -> signs (fp8, padded NHWC) + per-sample |x| sum + halo clear ----
__global__ __launch_bounds__(256) void k_xpad(const float* __restrict__ x,
                                              unsigned char* __restrict__ xpad,
                                              float* __restrict__ acc32) {
    int bx = blockIdx.x, n = blockIdx.y;
    {
        int g = (n * 196 + bx) * 256 + threadIdx.x;
        if (g < 32 * 228 * 16) {
            int n2 = g / 3648, rem = g - n2 * 3648;
            int pos = rem >> 4, j = rem & 15;
            int h, wq;
            if (pos < 58)       { h = 0;         wq = pos; }
            else if (pos < 116) { h = 57;        wq = pos - 58; }
            else if (pos < 172) { h = pos - 115; wq = 0; }
            else                { h = pos - 171; wq = 57; }
            *(i32x4*)&xpad[(((size_t)n2 * HP + h) * HP + wq) * 256 + j * 16] =
                (i32x4){0, 0, 0, 0};
        }
    }
    int hwt = bx % 49, ct = bx / 49;
    int hw0 = hwt * 64, c0 = ct * 64;
    int t = threadIdx.x, hwl = t & 63, cb = t >> 6;
    __shared__ unsigned char tile[64][68];
    __shared__ float red[4];
    float asum = 0.f;
    #pragma unroll
    for (int cc = 0; cc < 16; ++cc) {
        int cl = cb + cc * 4;
        float v = x[((size_t)(n * 256 + c0 + cl)) * HWP + hw0 + hwl];
        asum += fabsf(v);
        tile[hwl][cl] = sign_fp8(v);
    }
    #pragma unroll
    for (int off = 32; off; off >>= 1) asum += __shfl_down(asum, off, 64);
    if ((t & 63) == 0) red[t >> 6] = asum;
    __syncthreads();
    if (t == 0) atomicAdd(&acc32[n], red[0] + red[1] + red[2] + red[3]);
    int j = t & 15, rg = t >> 4;
    #pragma unroll
    for (int ps = 0; ps < 4; ++ps) {
        int hl = ps * 16 + rg;
        int hw = hw0 + hl, h = hw / 56, wp = hw - h * 56;
        unsigned int v4 = *(const unsigned int*)&tile[hl][4 * j];
        *(unsigned int*)&xpad[(((size_t)n * HP + h + 1) * HP + (wp + 1)) * 256 + c0 + 4 * j] = v4;
    }
}

// ---- K3: MX-fp8 implicit GEMM, barrier-free: wave-private X staging + reg A ----
// M=ko (2x128 grid.x), N=p (784x128 grid.y), K=2304 (18 steps of 128)
// Each wave consumes only X-rows [wn*64, wn*64+64) -> stages them privately;
// no __syncthreads in the K-loop; prefetch fenced by s_waitcnt vmcnt(16).
__global__ __launch_bounds__(256, 2) void k_gemm(const unsigned char* __restrict__ wA,
                                                 const unsigned char* __restrict__ xpad,
                                                 const float* __restrict__ acc32,
                                                 const float* __restrict__ msc,
                                                 float* __restrict__ out) {
    __shared__ __attribute__((aligned(16))) unsigned char Xt[4][2][8192];
    const int t = threadIdx.x;
    const int lane = t & 63, wv = t >> 6;
    const int mtile = blockIdx.x, ntile = blockIdx.y;
    const int quad = lane >> 4, r16 = lane & 15;
    const int wm = wv & 1, wn = wv >> 1;

    // staging: async16 slot rnd covers local rows rnd*8+(l>>3), phys cg = l&7.
    // chunk kc stored at phys perm(kc)^sw (sw=row&7=l>>3): kc = invperm((l&7)^(l>>3))
    const int lrow = lane >> 3;
    const int pxs  = (lane & 7) ^ lrow;
    const int kc   = ((pxs & 3) << 1) | (pxs >> 2);
    const unsigned char* xp[8];
    #pragma unroll
    for (int rnd = 0; rnd < 8; ++rnd) {
        int p = ntile * 128 + wn * 64 + rnd * 8 + lrow;
        int nimg = p / HWP, hw = p - nimg * HWP;
        int h = hw / 56, wpos = hw - h * 56;
        xp[rnd] = xpad + (((size_t)nimg * HP + h) * HP + wpos) * 256 + kc * 16;
    }
    unsigned char* xbuf0 = &Xt[wv][0][0];   // wave-uniform bases
    unsigned char* xbuf1 = &Xt[wv][1][0];

    // A: coalesced 1KB bursts, frag i lo at wbase + i*2048 + kt*32768, hi +1024
    const unsigned char* wbase =
        wA + ((size_t)(mtile * 8 + wm * 4) * 2) * 1024 + lane * 16;

    f32x4 acc[4][4];
    #pragma unroll
    for (int i = 0; i < 4; ++i)
        #pragma unroll
        for (int j = 0; j < 4; ++j)
            acc[i][j] = (f32x4){0.f, 0.f, 0.f, 0.f};

    i32x4 aLo[2][4], aHi[2][4];

    // prologue: stage X[0] into buf0, load A[0]  (16 vm ops outstanding)
    #pragma unroll
    for (int rnd = 0; rnd < 8; ++rnd)
        async16(xp[rnd] + xoff(0), xbuf0 + rnd * 1024);
    #pragma unroll
    for (int i = 0; i < 4; ++i) {
        aLo[0][i] = *(const i32x4*)(wbase + i * 2048);
        aHi[0][i] = *(const i32x4*)(wbase + i * 2048 + 1024);
    }

    #pragma unroll 2
    for (int kt = 0; kt < 18; ++kt) {
        const int cur = kt & 1;
        if (kt < 17) {
            int o = xoff(kt + 1);
            unsigned char* nb = cur ? xbuf0 : xbuf1;
            #pragma unroll
            for (int rnd = 0; rnd < 8; ++rnd)
                async16(xp[rnd] + o, nb + rnd * 1024);
            const unsigned char* wnext = wbase + (size_t)(kt + 1) * 32768;
            #pragma unroll
            for (int i = 0; i < 4; ++i) {
                aLo[1 - cur][i] = *(const i32x4*)(wnext + i * 2048);
                aHi[1 - cur][i] = *(const i32x4*)(wnext + i * 2048 + 1024);
            }
            // drain the PREVIOUS iteration's 16 vm ops; keep the 16 just issued
            asm volatile("s_waitcnt vmcnt(16)" ::: "memory");
        } else {
            asm volatile("s_waitcnt vmcnt(0)" ::: "memory");
        }
        const unsigned char* xb = cur ? xbuf1 : xbuf0;
        i32x8 b8[4];
        #pragma unroll
        for (int j = 0; j < 4; ++j) {
            int slot = j * 2 + (r16 >> 3), sw = r16 & 7;
            i32x4 lo = *(const i32x4*)(xb + slot * 1024 + sw * 128 + ((quad ^ sw) << 4));
            i32x4 hi = *(const i32x4*)(xb + slot * 1024 + sw * 128 + (((quad | 4) ^ sw) << 4));
            b8[j] = __builtin_shufflevector(lo, hi, 0, 1, 2, 3, 4, 5, 6, 7);
        }
        #pragma unroll
        for (int i = 0; i < 4; ++i) {
            i32x8 a8 = __builtin_shufflevector(aLo[cur][i], aHi[cur][i],
                                               0, 1, 2, 3, 4, 5, 6, 7);
            #pragma unroll
            for (int j = 0; j < 4; ++j)
                acc[i][j] = __builtin_amdgcn_mfma_scale_f32_16x16x128_f8f6f4(
                    a8, b8[j], acc[i][j], 0, 0, 0, 127, 0, 127);
        }
    }

    // epilogue: D row (quad*4+reg)=ko, D col (lane&15)=p
    float mscv[4][4];
    #pragma unroll
    for (int i = 0; i < 4; ++i) {
        int ko0 = mtile * 128 + wm * 64 + i * 16 + quad * 4;
        #pragma unroll
        for (int r = 0; r < 4; ++r) mscv[i][r] = msc[ko0 + r];
    }
    #pragma unroll
    for (int j = 0; j < 4; ++j) {
        int p = ntile * 128 + wn * 64 + j * 16 + r16;
        int nimg = p / HWP, hw = p - nimg * HWP;
        float av = fmaxf(acc32[nimg] * (2.f / 802816.f), 1e-5f);
        float* outp = out + (size_t)nimg * 802816 + hw;
        #pragma unroll
        for (int i = 0; i < 4; ++i) {
            int ko0 = mtile * 128 + wm * 64 + i * 16 + quad * 4;
            #pragma unroll
            for (int r = 0; r < 4; ++r)
                outp[(size_t)(ko0 + r) * HWP] = acc[i][j][r] * av * mscv[i][r];
        }
    }
}

extern "C" void kernel_launch(void* const* d_in, const int* in_sizes, int n_in,
                              void* d_out, int out_size, void* d_ws, size_t ws_size,
                              hipStream_t stream) {
    const float* x = (const float*)d_in[0];
    const float* w = (const float*)d_in[1];
    float* out = (float*)d_out;
    char* ws = (char*)d_ws;
    unsigned char* xpad = (unsigned char*)(ws + OFF_XPAD);
    unsigned char* wA   = (unsigned char*)(ws + OFF_WSGN);
    float* msc   = (float*)(ws + OFF_MSC);
    float* acc32 = (float*)(ws + OFF_ACC);

    k_wm<<<256, 256, 0, stream>>>(w, wA, msc, acc32);
    k_xpad<<<dim3(196, N_IMG), 256, 0, stream>>>(x, xpad, acc32);
    k_gemm<<<dim3(2, 784), 256, 0, stream>>>(wA, xpad, acc32, msc, out);
}

// Round 6
// 276.766 us; speedup vs baseline: 1.7049x; 1.5491x over previous
//
#include <hip/hip_runtime.h>
#include <cstdint>

typedef int   i32x4 __attribute__((ext_vector_type(4)));
typedef int   i32x8 __attribute__((ext_vector_type(8)));
typedef float f32x4 __attribute__((ext_vector_type(4)));

static constexpr int N_IMG = 32, HWP = 3136, KK = 2304, HP = 58;
static constexpr size_t XPAD_BYTES = (size_t)N_IMG * HP * HP * 256;   // 27,553,792
static constexpr size_t OFF_XPAD = 0;
static constexpr size_t OFF_WSGN = XPAD_BYTES;                         // +589,824
static constexpr size_t OFF_MSC  = OFF_WSGN + (size_t)256 * KK;
static constexpr size_t OFF_ACC  = OFF_MSC + 1024;

__device__ __forceinline__ void async16(const void* g, const void* l) {
    __builtin_amdgcn_global_load_lds(
        (const __attribute__((address_space(1))) uint32_t*)g,
        (__attribute__((address_space(3))) uint32_t*)l, 16, 0, 0);
}

__device__ __forceinline__ unsigned char sign_fp8(float v) {
    return (v > 0.f) ? 0x38u : ((v < 0.f) ? 0xB8u : 0u);   // e4m3: +1 / -1 / 0
}

// X-tile K-slice byte offset within a padded NHWC row for K-step kt (K=128)
__device__ __forceinline__ int xoff(int kt) {
    int rs = kt >> 1, rr = rs / 3, ss = rs - rr * 3;
    return (rr * HP + ss) * 256 + ((kt & 1) << 7);
}

// ---- K1: weights -> signs in [kt][row 0..255][128B] layout + msc + zero acc32 ----
__global__ __launch_bounds__(256) void k_wm(const float* __restrict__ w,
                                            unsigned char* __restrict__ wA,
                                            float* __restrict__ msc,
                                            float* __restrict__ acc32) {
    int ko = blockIdx.x, t = threadIdx.x;
    __shared__ unsigned char s[2304];
    __shared__ float red[4];
    float sum = 0.f;
    #pragma unroll
    for (int i = 0; i < 9; ++i) {
        float v = w[(size_t)ko * KK + i * 256 + t];   // flat idx = c*9+rs order
        sum += fabsf(v);
        s[i * 256 + t] = sign_fp8(v);
    }
    #pragma unroll
    for (int off = 32; off; off >>= 1) sum += __shfl_down(sum, off, 64);
    if ((t & 63) == 0) red[t >> 6] = sum;
    __syncthreads();
    if (t == 0) msc[ko] = (red[0] + red[1] + red[2] + red[3]) * (1.f / 2304.f);
    if (ko == 0 && t < 32) acc32[t] = 0.f;
    // k = rs*256 + c with rs=i, c=t ; value = s[t*9+i] = sign(w[ko][c=t][rs=i])
    #pragma unroll
    for (int i = 0; i < 9; ++i)
        wA[((size_t)(i * 2 + (t >> 7)) * 256 + ko) * 128 + (t & 127)] = s[t * 9 + i];
}

// ---- K2: x -> signs (fp8, padded NHWC) + per-sample |x| sum + halo clear ----
__global__ __launch_bounds__(256) void k_xpad(const float* __restrict__ x,
                                              unsigned char* __restrict__ xpad,
                                              float* __restrict__ acc32) {
    int bx = blockIdx.x, n = blockIdx.y;
    {
        int g = (n * 196 + bx) * 256 + threadIdx.x;
        if (g < 32 * 228 * 16) {
            int n2 = g / 3648, rem = g - n2 * 3648;
            int pos = rem >> 4, j = rem & 15;
            int h, wq;
            if (pos < 58)       { h = 0;         wq = pos; }
            else if (pos < 116) { h = 57;        wq = pos - 58; }
            else if (pos < 172) { h = pos - 115; wq = 0; }
            else                { h = pos - 171; wq = 57; }
            *(i32x4*)&xpad[(((size_t)n2 * HP + h) * HP + wq) * 256 + j * 16] =
                (i32x4){0, 0, 0, 0};
        }
    }
    int hwt = bx % 49, ct = bx / 49;
    int hw0 = hwt * 64, c0 = ct * 64;
    int t = threadIdx.x, hwl = t & 63, cb = t >> 6;
    __shared__ unsigned char tile[64][68];
    __shared__ float red[4];
    float asum = 0.f;
    #pragma unroll
    for (int cc = 0; cc < 16; ++cc) {
        int cl = cb + cc * 4;
        float v = x[((size_t)(n * 256 + c0 + cl)) * HWP + hw0 + hwl];
        asum += fabsf(v);
        tile[hwl][cl] = sign_fp8(v);
    }
    #pragma unroll
    for (int off = 32; off; off >>= 1) asum += __shfl_down(asum, off, 64);
    if ((t & 63) == 0) red[t >> 6] = asum;
    __syncthreads();
    if (t == 0) atomicAdd(&acc32[n], red[0] + red[1] + red[2] + red[3]);
    int j = t & 15, rg = t >> 4;
    #pragma unroll
    for (int ps = 0; ps < 4; ++ps) {
        int hl = ps * 16 + rg;
        int hw = hw0 + hl, h = hw / 56, wp = hw - h * 56;
        unsigned int v4 = *(const unsigned int*)&tile[hl][4 * j];
        *(unsigned int*)&xpad[(((size_t)n * HP + h + 1) * HP + (wp + 1)) * 256 + c0 + 4 * j] = v4;
    }
}

// ---- K3: MX-fp8 implicit GEMM (R2 structure: block-coop LDS staging, 2 barriers)
// + perm swizzle on both tiles (verified 0-conflict) + 3 blocks/CU.
// M=ko (2x128 grid.x), N=p (784x128 grid.y), K=2304 (18 steps of 128)
__global__ __launch_bounds__(256, 3) void k_gemm(const unsigned char* __restrict__ wA,
                                                 const unsigned char* __restrict__ xpad,
                                                 const float* __restrict__ acc32,
                                                 const float* __restrict__ msc,
                                                 float* __restrict__ out) {
    __shared__ __attribute__((aligned(16))) unsigned char Wt[128 * 128];
    __shared__ __attribute__((aligned(16))) unsigned char Xt[128 * 128];
    const int t = threadIdx.x;
    const int lane = t & 63, wv = t >> 6;
    const int mtile = blockIdx.x, ntile = blockIdx.y;
    const int quad = lane >> 4, r16 = lane & 15;
    const int wm = wv & 1, wn = wv >> 1;

    // staging: lane l fills slot base + l*16 -> row = slotbase + (l>>3), phys cg = l&7.
    // logical chunk kc stored at phys perm(kc)^sw, perm(kc)=(kc>>1)|((kc&1)<<2), sw=row&7.
    // source kc = invperm((l&7)^(l>>3)), invperm(p)=((p&3)<<1)|(p>>2).
    const int lrow = lane >> 3;
    const int pxs  = (lane & 7) ^ lrow;
    const int kc   = ((pxs & 3) << 1) | (pxs >> 2);

    const unsigned char* wp[4];
    const unsigned char* xp[4];
    unsigned char* ldsW[4];
    unsigned char* ldsX[4];
    #pragma unroll
    for (int rnd = 0; rnd < 4; ++rnd) {
        int row = (wv * 4 + rnd) * 8 + lrow;          // 0..127
        wp[rnd] = wA + (size_t)(mtile * 128 + row) * 128 + kc * 16;   // + kt*32768
        int p = ntile * 128 + row;
        int nimg = p / HWP, hw = p - nimg * HWP;
        int h = hw / 56, wpos = hw - h * 56;
        xp[rnd] = xpad + (((size_t)nimg * HP + h) * HP + wpos) * 256 + kc * 16;
        ldsW[rnd] = Wt + (wv * 4 + rnd) * 1024;
        ldsX[rnd] = Xt + (wv * 4 + rnd) * 1024;
    }

    f32x4 acc[4][4];
    #pragma unroll
    for (int i = 0; i < 4; ++i)
        #pragma unroll
        for (int j = 0; j < 4; ++j)
            acc[i][j] = (f32x4){0.f, 0.f, 0.f, 0.f};

    for (int kt = 0; kt < 18; ++kt) {
        const size_t offW = (size_t)kt * 32768;
        const int offX = xoff(kt);
        #pragma unroll
        for (int rnd = 0; rnd < 4; ++rnd) async16(wp[rnd] + offW, ldsW[rnd]);
        #pragma unroll
        for (int rnd = 0; rnd < 4; ++rnd) async16(xp[rnd] + offX, ldsX[rnd]);
        asm volatile("s_waitcnt vmcnt(0)" ::: "memory");
        __syncthreads();

        // reads: lo at phys (q^sw), hi at ((q|4)^sw) — bit-2 pair, measured 0-conflict
        i32x8 b8[4];
        #pragma unroll
        for (int j = 0; j < 4; ++j) {
            int row = wn * 64 + j * 16 + r16, sw = row & 7;
            i32x4 lo = *(const i32x4*)(Xt + row * 128 + ((quad ^ sw) << 4));
            i32x4 hi = *(const i32x4*)(Xt + row * 128 + (((quad | 4) ^ sw) << 4));
            b8[j] = __builtin_shufflevector(lo, hi, 0, 1, 2, 3, 4, 5, 6, 7);
        }
        #pragma unroll
        for (int i = 0; i < 4; ++i) {
            int row = wm * 64 + i * 16 + r16, sw = row & 7;
            i32x4 lo = *(const i32x4*)(Wt + row * 128 + ((quad ^ sw) << 4));
            i32x4 hi = *(const i32x4*)(Wt + row * 128 + (((quad | 4) ^ sw) << 4));
            i32x8 a8 = __builtin_shufflevector(lo, hi, 0, 1, 2, 3, 4, 5, 6, 7);
            #pragma unroll
            for (int j = 0; j < 4; ++j)
                acc[i][j] = __builtin_amdgcn_mfma_scale_f32_16x16x128_f8f6f4(
                    a8, b8[j], acc[i][j], 0, 0, 0, 127, 0, 127);
        }
        __syncthreads();
    }

    // epilogue: D row (quad*4+reg)=ko, D col (lane&15)=p
    float mscv[4][4];
    #pragma unroll
    for (int i = 0; i < 4; ++i) {
        int ko0 = mtile * 128 + wm * 64 + i * 16 + quad * 4;
        #pragma unroll
        for (int r = 0; r < 4; ++r) mscv[i][r] = msc[ko0 + r];
    }
    #pragma unroll
    for (int j = 0; j < 4; ++j) {
        int p = ntile * 128 + wn * 64 + j * 16 + r16;
        int nimg = p / HWP, hw = p - nimg * HWP;
        float av = fmaxf(acc32[nimg] * (2.f / 802816.f), 1e-5f);
        float* outp = out + (size_t)nimg * 802816 + hw;
        #pragma unroll
        for (int i = 0; i < 4; ++i) {
            int ko0 = mtile * 128 + wm * 64 + i * 16 + quad * 4;
            #pragma unroll
            for (int r = 0; r < 4; ++r)
                outp[(size_t)(ko0 + r) * HWP] = acc[i][j][r] * av * mscv[i][r];
        }
    }
}

extern "C" void kernel_launch(void* const* d_in, const int* in_sizes, int n_in,
                              void* d_out, int out_size, void* d_ws, size_t ws_size,
                              hipStream_t stream) {
    const float* x = (const float*)d_in[0];
    const float* w = (const float*)d_in[1];
    float* out = (float*)d_out;
    char* ws = (char*)d_ws;
    unsigned char* xpad = (unsigned char*)(ws + OFF_XPAD);
    unsigned char* wA   = (unsigned char*)(ws + OFF_WSGN);
    float* msc   = (float*)(ws + OFF_MSC);
    float* acc32 = (float*)(ws + OFF_ACC);

    k_wm<<<256, 256, 0, stream>>>(w, wA, msc, acc32);
    k_xpad<<<dim3(196, N_IMG), 256, 0, stream>>>(x, xpad, acc32);
    k_gemm<<<dim3(2, 784), 256, 0, stream>>>(wA, xpad, acc32, msc, out);
}